// Round 1
// baseline (3994.598 us; speedup 1.0000x reference)
//
#include <hip/hip_runtime.h>
#include <hip/hip_bf16.h>
#include <cstdint>
#include <math.h>

#define BH 24
#define S 2048
#define D 64
#define CTX_ELEMS ((size_t)BH * S * D)   /* 3145728 floats: context output */
#define SDP_SCALE 0.5f
#define MASK_FILL -1.0e9f

// K1: one wave per query row. Computes raw masked scores -> attn slot of out
// (scratch; overwritten by K2 with normalized probs). Tracks online row max m
// and sum-of-exp l, stores them at out[row*64 + {0,1}] (context slot, later
// overwritten by the SAME block in K2 -> no cross-block hazard).
__global__ __launch_bounds__(256) void sdpa_scores(
    const float* __restrict__ q, const float* __restrict__ k,
    const int* __restrict__ mask, float* __restrict__ out)
{
    const int wave = threadIdx.x >> 6;
    const int lane = threadIdx.x & 63;
    const int rid  = blockIdx.x * 4 + wave;   // global row id in [0, BH*S)
    const int bh   = rid >> 11;               // row / S

    __shared__ float qs[4][64];
    qs[wave][lane] = q[(size_t)rid * D + lane];
    __syncthreads();

    const float4* __restrict__ k4 = (const float4*)(k + (size_t)bh * S * D);
    const int*    __restrict__ mrow = mask + (size_t)rid * S;
    float*        __restrict__ arow = out + CTX_ELEMS + (size_t)rid * S;
    const float4* __restrict__ q4 = (const float4*)qs[wave];

    float m = -INFINITY, l = 0.0f;
    for (int t = 0; t < S / 64; ++t) {
        const int c = t * 64 + lane;
        float s = 0.0f;
        #pragma unroll
        for (int d4 = 0; d4 < 16; ++d4) {
            float4 qv = q4[d4];
            float4 kv = k4[(size_t)c * 16 + d4];
            s += qv.x * kv.x + qv.y * kv.y + qv.z * kv.z + qv.w * kv.w;
        }
        s *= SDP_SCALE;
        if (mrow[c] != 0) s = MASK_FILL;   // mask==True -> fill
        arow[c] = s;                        // raw masked score (scratch)
        // online max/sum (s is always finite >= -1e9, so no inf-inf NaN)
        float mn = fmaxf(m, s);
        l = l * __expf(m - mn) + __expf(s - mn);
        m = mn;
    }
    // butterfly reduce (m, l) across the 64 lanes
    #pragma unroll
    for (int off = 32; off >= 1; off >>= 1) {
        float m2 = __shfl_xor(m, off, 64);
        float l2 = __shfl_xor(l, off, 64);
        float mn = fmaxf(m, m2);
        l = l * __expf(m - mn) + l2 * __expf(m2 - mn);
        m = mn;
    }
    if (lane == 0) {
        out[(size_t)rid * D + 0] = m;
        out[(size_t)rid * D + 1] = l;
    }
}

// K2: block = 256 threads (4 waves), 16 rows per block (4 rows/wave).
// Reads per-row stats, streams over 32 column tiles of 64: stages V tile and
// normalized P tile in LDS, writes normalized attn, accumulates context.
__global__ __launch_bounds__(256) void sdpa_context(
    const float* __restrict__ v, float* __restrict__ out)
{
    const int t    = threadIdx.x;
    const int wave = t >> 6;
    const int lane = t & 63;
    const int rbase = blockIdx.x * 16;   // 16 rows, all within one head (2048%16==0)
    const int bh    = rbase >> 11;

    __shared__ float vS[64][64];   // vS[jj][d]: bank = d%32 -> conflict-free
    __shared__ float pS[16][64];
    __shared__ float mS[16], invlS[16];

    if (t < 16) {
        mS[t]    = out[(size_t)(rbase + t) * D + 0];
        invlS[t] = 1.0f / out[(size_t)(rbase + t) * D + 1];   // l >= 1 always
    }
    __syncthreads();

    const float* __restrict__ vhead = v + (size_t)bh * S * D;
    float* __restrict__ attn = out + CTX_ELEMS;

    float acc[4] = {0.f, 0.f, 0.f, 0.f};
    for (int jt = 0; jt < S / 64; ++jt) {
        // stage V tile (64 cols x 64 d), coalesced
        #pragma unroll
        for (int i = 0; i < 16; ++i) {
            int idx = i * 256 + t;
            vS[idx >> 6][idx & 63] = vhead[(size_t)jt * 4096 + idx];
        }
        // stage P tile (16 rows x 64 cols): normalize raw scores, write attn
        #pragma unroll
        for (int i = 0; i < 4; ++i) {
            int idx = i * 256 + t;
            int row = idx >> 6, jj = idx & 63;
            size_t g = (size_t)(rbase + row) * S + (size_t)jt * 64 + jj;
            float p = __expf(attn[g] - mS[row]) * invlS[row];
            attn[g] = p;
            pS[row][jj] = p;
        }
        __syncthreads();
        // context accumulation: 4 rows per wave amortize the vS read
        #pragma unroll 8
        for (int jj = 0; jj < 64; ++jj) {
            float vv = vS[jj][lane];
            #pragma unroll
            for (int rr = 0; rr < 4; ++rr)
                acc[rr] += pS[wave * 4 + rr][jj] * vv;   // pS read = broadcast
        }
        __syncthreads();
    }
    #pragma unroll
    for (int rr = 0; rr < 4; ++rr)
        out[(size_t)(rbase + wave * 4 + rr) * D + lane] = acc[rr];
}

extern "C" void kernel_launch(void* const* d_in, const int* in_sizes, int n_in,
                              void* d_out, int out_size, void* d_ws, size_t ws_size,
                              hipStream_t stream) {
    const float* q    = (const float*)d_in[0];
    const float* k    = (const float*)d_in[1];
    const float* v    = (const float*)d_in[2];
    const int*   mask = (const int*)d_in[3];
    float* out = (float*)d_out;

    sdpa_scores<<<BH * S / 4, 256, 0, stream>>>(q, k, mask, out);
    sdpa_context<<<BH * S / 16, 256, 0, stream>>>(v, out);
}

// Round 2
// 941.996 us; speedup vs baseline: 4.2406x; 4.2406x over previous
//
#include <hip/hip_runtime.h>
#include <hip/hip_bf16.h>
#include <cstdint>
#include <math.h>

#define S 2048
#define D 64
#define CTX_ELEMS ((size_t)24 * S * D)   /* context output elems */
#define SDP_SCALE 0.5f
#define MASK_FILL -1.0e9f
#define LDP 72                            /* padded LDS row stride (bf16 elems) */

typedef __attribute__((ext_vector_type(8))) short   bf16x8;
typedef __attribute__((ext_vector_type(4))) float   f32x4;
typedef __attribute__((ext_vector_type(4))) unsigned short us4;

__device__ __forceinline__ unsigned short f2bf(float x) {
    unsigned u = __builtin_bit_cast(unsigned, x);
    u += 0x7FFFu + ((u >> 16) & 1u);          // RNE
    return (unsigned short)(u >> 16);
}
__device__ __forceinline__ float bf2f(unsigned short b) {
    unsigned u = ((unsigned)b) << 16;
    return __builtin_bit_cast(float, u);
}

// ---------------- Pass A: split-bf16 MFMA QK^T, mask, raw scores + (m,l) ---
// Block = 256 thr (4 waves), 64 Q rows. Wave w owns rows [w*16, w*16+16).
// MFMA 16x16x32: A[m=lane&15][k=quad*8+j]; B[k=quad*8+j][n=lane&15];
// C/D: col=lane&15, row=quad*4+reg  (m89/m120-verified layouts).
__global__ __launch_bounds__(256) void sdpa_pass_a(
    const float* __restrict__ q, const float* __restrict__ k,
    const int* __restrict__ mask, float* __restrict__ out)
{
    const int t = threadIdx.x;
    const int wv = t >> 6, lane = t & 63;
    const int quad = lane >> 4, n = lane & 15;
    const int rbase = blockIdx.x * 64;        // 64 rows, within one head
    const int bh = rbase >> 11;

    __shared__ unsigned short qhi[64 * LDP], qlo[64 * LDP];
    __shared__ unsigned short khi[64 * LDP], klo[64 * LDP];

    // stage Q tile (64x64 fp32, contiguous), split hi/lo bf16
    const float4* q4 = (const float4*)(q + (size_t)rbase * D);
    #pragma unroll
    for (int i = 0; i < 4; ++i) {
        int idx = i * 256 + t;                // 1024 float4 = 64 rows x 16
        int row = idx >> 4, c4 = (idx & 15) * 4;
        float4 val = q4[idx];
        float c[4] = {val.x, val.y, val.z, val.w};
        us4 h, l;
        #pragma unroll
        for (int u = 0; u < 4; ++u) {
            unsigned short hb = f2bf(c[u]);
            h[u] = hb;
            l[u] = f2bf(c[u] - bf2f(hb));
        }
        *(us4*)&qhi[row * LDP + c4] = h;
        *(us4*)&qlo[row * LDP + c4] = l;
    }
    __syncthreads();

    // hoist Q fragments (constant over all K tiles)
    bf16x8 qfh[2], qfl[2];
    #pragma unroll
    for (int ks = 0; ks < 2; ++ks) {
        const unsigned short* p = &qhi[(wv * 16 + n) * LDP + ks * 32 + quad * 8];
        qfh[ks] = *(const bf16x8*)p;
        p = &qlo[(wv * 16 + n) * LDP + ks * 32 + quad * 8];
        qfl[ks] = *(const bf16x8*)p;
    }

    float m_r[4] = {-INFINITY, -INFINITY, -INFINITY, -INFINITY};
    float l_r[4] = {0.f, 0.f, 0.f, 0.f};

    const float* khead = k + (size_t)bh * S * D;
    for (int jt = 0; jt < S / 64; ++jt) {
        // stage K tile (rows jt*64..+64 of head, contiguous 16 KB)
        const float4* k4 = (const float4*)(khead + (size_t)jt * 64 * D);
        #pragma unroll
        for (int i = 0; i < 4; ++i) {
            int idx = i * 256 + t;
            int row = idx >> 4, c4 = (idx & 15) * 4;
            float4 val = k4[idx];
            float c[4] = {val.x, val.y, val.z, val.w};
            us4 h, l;
            #pragma unroll
            for (int u = 0; u < 4; ++u) {
                unsigned short hb = f2bf(c[u]);
                h[u] = hb;
                l[u] = f2bf(c[u] - bf2f(hb));
            }
            *(us4*)&khi[row * LDP + c4] = h;
            *(us4*)&klo[row * LDP + c4] = l;
        }
        __syncthreads();

        f32x4 acc[4];
        #pragma unroll
        for (int ct = 0; ct < 4; ++ct) {
            f32x4 c = {0.f, 0.f, 0.f, 0.f};
            #pragma unroll
            for (int ks = 0; ks < 2; ++ks) {
                const unsigned short* bp = &khi[(ct * 16 + n) * LDP + ks * 32 + quad * 8];
                bf16x8 bh_ = *(const bf16x8*)bp;
                bp = &klo[(ct * 16 + n) * LDP + ks * 32 + quad * 8];
                bf16x8 bl_ = *(const bf16x8*)bp;
                c = __builtin_amdgcn_mfma_f32_16x16x32_bf16(qfh[ks], bh_, c, 0, 0, 0);
                c = __builtin_amdgcn_mfma_f32_16x16x32_bf16(qfl[ks], bh_, c, 0, 0, 0);
                c = __builtin_amdgcn_mfma_f32_16x16x32_bf16(qfh[ks], bl_, c, 0, 0, 0);
            }
            acc[ct] = c;
        }

        // mask, store raw scores, online (m,l) per owned row
        #pragma unroll
        for (int r = 0; r < 4; ++r) {
            const int rowg = rbase + wv * 16 + quad * 4 + r;
            const int* mrowp = mask + (size_t)rowg * S + jt * 64;
            float* arowp = out + CTX_ELEMS + (size_t)rowg * S + jt * 64;
            float vals[4];
            float vmax = -INFINITY;
            #pragma unroll
            for (int ct = 0; ct < 4; ++ct) {
                float s = acc[ct][r] * SDP_SCALE;
                if (mrowp[ct * 16 + n] != 0) s = MASK_FILL;
                arowp[ct * 16 + n] = s;
                vals[ct] = s;
                vmax = fmaxf(vmax, s);
            }
            #pragma unroll
            for (int off = 1; off < 16; off <<= 1)
                vmax = fmaxf(vmax, __shfl_xor(vmax, off, 64));
            float mnew = fmaxf(m_r[r], vmax);
            float ssum = 0.f;
            #pragma unroll
            for (int ct = 0; ct < 4; ++ct) ssum += __expf(vals[ct] - mnew);
            #pragma unroll
            for (int off = 1; off < 16; off <<= 1)
                ssum += __shfl_xor(ssum, off, 64);
            l_r[r] = l_r[r] * __expf(m_r[r] - mnew) + ssum;
            m_r[r] = mnew;
        }
        __syncthreads();
    }

    // stash (m, l) in context slot (same rows overwritten by pass B's block)
    if (n == 0) {
        #pragma unroll
        for (int r = 0; r < 4; ++r) {
            const int rowg = rbase + wv * 16 + quad * 4 + r;
            out[(size_t)rowg * D + 0] = m_r[r];
            out[(size_t)rowg * D + 1] = l_r[r];
        }
    }
}

// ---------------- Pass B: normalize -> attn, MFMA P*V -> context ----------
__global__ __launch_bounds__(256) void sdpa_pass_b(
    const float* __restrict__ v, float* __restrict__ out)
{
    const int t = threadIdx.x;
    const int wv = t >> 6, lane = t & 63;
    const int quad = lane >> 4, n = lane & 15;
    const int rbase = blockIdx.x * 64;
    const int bh = rbase >> 11;

    __shared__ unsigned short pS[64 * LDP];
    __shared__ float mS[64], ilS[64];

    if (t < 64) {
        mS[t]  = out[(size_t)(rbase + t) * D + 0];
        ilS[t] = 1.0f / out[(size_t)(rbase + t) * D + 1];   // l >= ~1 always
    }
    __syncthreads();

    float* attn = out + CTX_ELEMS;
    const float* vhead = v + (size_t)bh * S * D;

    f32x4 acc[4] = {{0.f,0.f,0.f,0.f},{0.f,0.f,0.f,0.f},
                    {0.f,0.f,0.f,0.f},{0.f,0.f,0.f,0.f}};

    for (int jt = 0; jt < S / 64; ++jt) {
        // stage P tile: read raw scores, normalize, write attn, bf16 -> LDS
        #pragma unroll
        for (int i = 0; i < 4; ++i) {
            int idx = i * 256 + t;
            int row = idx >> 4, c4 = (idx & 15) * 4;
            float4* p4 = (float4*)(attn + (size_t)(rbase + row) * S + jt * 64 + c4);
            float4 sv = *p4;
            float mm = mS[row], il = ilS[row];
            sv.x = __expf(sv.x - mm) * il;
            sv.y = __expf(sv.y - mm) * il;
            sv.z = __expf(sv.z - mm) * il;
            sv.w = __expf(sv.w - mm) * il;
            *p4 = sv;
            us4 pb = { f2bf(sv.x), f2bf(sv.y), f2bf(sv.z), f2bf(sv.w) };
            *(us4*)&pS[row * LDP + c4] = pb;
        }
        __syncthreads();

        // A-frags (per ks) from pS; B-frags from global V (L1/L2-resident)
        bf16x8 af[2];
        #pragma unroll
        for (int ks = 0; ks < 2; ++ks)
            af[ks] = *(const bf16x8*)&pS[(wv * 16 + n) * LDP + ks * 32 + quad * 8];

        #pragma unroll
        for (int dt = 0; dt < 4; ++dt) {
            #pragma unroll
            for (int ks = 0; ks < 2; ++ks) {
                const int kg = jt * 64 + ks * 32 + quad * 8;
                const float* vp = vhead + (size_t)kg * D + dt * 16 + n;
                bf16x8 b;
                #pragma unroll
                for (int j = 0; j < 8; ++j) b[j] = (short)f2bf(vp[(size_t)j * D]);
                acc[dt] = __builtin_amdgcn_mfma_f32_16x16x32_bf16(af[ks], b, acc[dt], 0, 0, 0);
            }
        }
        __syncthreads();
    }

    // write context (overwrites the (m,l) stash)
    #pragma unroll
    for (int dt = 0; dt < 4; ++dt) {
        #pragma unroll
        for (int r = 0; r < 4; ++r) {
            const int rowg = rbase + wv * 16 + quad * 4 + r;
            out[(size_t)rowg * D + dt * 16 + n] = acc[dt][r];
        }
    }
}

extern "C" void kernel_launch(void* const* d_in, const int* in_sizes, int n_in,
                              void* d_out, int out_size, void* d_ws, size_t ws_size,
                              hipStream_t stream) {
    const float* q    = (const float*)d_in[0];
    const float* k    = (const float*)d_in[1];
    const float* v    = (const float*)d_in[2];
    const int*   mask = (const int*)d_in[3];
    float* out = (float*)d_out;

    sdpa_pass_a<<<24 * S / 64, 256, 0, stream>>>(q, k, mask, out);
    sdpa_pass_b<<<24 * S / 64, 256, 0, stream>>>(v, out);
}